// Round 5
// baseline (117072.876 us; speedup 1.0000x reference)
//
#include <hip/hip_runtime.h>

typedef __attribute__((ext_vector_type(4))) float f32x4;
typedef __attribute__((ext_vector_type(8))) short short8;
typedef __attribute__((ext_vector_type(4))) unsigned int u32x4;
typedef __attribute__((ext_vector_type(2))) unsigned int u32x2;

#define T_LEN 4096
#define SENTP 0x7FC07FC0u  // bf16 NaN pair — h is always finite
#define SENT64 0x7FC07FC07FC07FC0ULL

__device__ __forceinline__ float bf2f(unsigned short u) {
  return __uint_as_float(((unsigned int)u) << 16);
}
__device__ __forceinline__ unsigned short f2bf(float f) {
  unsigned int x = __float_as_uint(f);
  unsigned int r = (x + 0x7fffu + ((x >> 16) & 1u)) >> 16;
  return (unsigned short)r;
}
__device__ __forceinline__ unsigned int pk2(float a, float b) {
  return (unsigned int)f2bf(a) | ((unsigned int)f2bf(b) << 16);
}
__device__ __forceinline__ float sigm(float x) { return 1.f / (1.f + __expf(-x)); }
__device__ __forceinline__ float tanh_f(float x) { return 2.f / (1.f + __expf(-2.f * x)) - 1.f; }

#if __has_builtin(__builtin_amdgcn_fdot2_f32_bf16)
typedef __attribute__((ext_vector_type(2))) short bf16x2;
__device__ __forceinline__ float dot2bf(unsigned int w, unsigned int h, float c) {
  bf16x2 a, b;
  __builtin_memcpy(&a, &w, 4);
  __builtin_memcpy(&b, &h, 4);
  return __builtin_amdgcn_fdot2_f32_bf16(a, b, c, false);
}
#else
__device__ __forceinline__ float dot2bf(unsigned int w, unsigned int h, float c) {
  float wl = __uint_as_float(w << 16), wh = __uint_as_float(w & 0xffff0000u);
  float hl = __uint_as_float(h << 16), hh = __uint_as_float(h & 0xffff0000u);
  return c + wl * hl + wh * hh;
}
#endif

__device__ __forceinline__ bool okq(unsigned long long v) {
  return ((unsigned int)v != SENTP) && ((unsigned int)(v >> 32) != SENTP);
}

// DPP row_ror reduction stage: a += rotate-within-16-row(a). CTRL is a template
// parameter because __builtin_amdgcn_update_dpp requires a literal control.
template <int CTRL>
__device__ __forceinline__ float ror_add(float a) {
  int r = __builtin_amdgcn_update_dpp(0, __float_as_int(a), CTRL, 0xf, 0xf, true);
  return a + __int_as_float(r);
}
// Full 64-lane sum, result broadcast to every lane.
__device__ __forceinline__ float wave_sum64(float a) {
  a = ror_add<0x121>(a);  // row_ror:1
  a = ror_add<0x122>(a);  // row_ror:2
  a = ror_add<0x124>(a);  // row_ror:4
  a = ror_add<0x128>(a);  // row_ror:8  -> full 16-row sum on all lanes
  a += __shfl_xor(a, 16, 64);
  a += __shfl_xor(a, 32, 64);
  return a;
}

// ---------------- init: convert x -> bf16, poison hbuf ----------------
__global__ void init_conv(const float* __restrict__ x, unsigned short* __restrict__ xbf,
                          unsigned int* __restrict__ hbuf) {
  int gid = blockIdx.x * 256 + threadIdx.x;
  const int stride = gridDim.x * 256;
  const int n4 = (T_LEN * 2048) / 4;
  for (int i = gid; i < n4; i += stride) {
    f32x4 v = *(const f32x4*)(x + (size_t)i * 4);
    u32x2 u;
    u[0] = pk2(v[0], v[1]);
    u[1] = pk2(v[2], v[3]);
    *(u32x2*)(xbf + (size_t)i * 4) = u;
  }
  u32x4 s4;
  s4[0] = s4[1] = s4[2] = s4[3] = SENTP;
  const int nh = (2 * T_LEN * 512) / 4;  // hbuf x4-chunks
  for (int i = gid; i < nh; i += stride) *(u32x4*)(hbuf + (size_t)i * 4) = s4;
}

// ---------------- pre = seq @ w_ih.T + b_ih + b_hh  (bf16 MFMA GEMM) ----------------
// Prologue: also converts this layer's W_hh (fp32) -> whhb (bf16), 4096 floats/block.
__global__ __launch_bounds__(256) void gemm_pre(
    const unsigned short* __restrict__ A, const float* __restrict__ W,
    const float* __restrict__ bih, const float* __restrict__ bhh,
    unsigned short* __restrict__ pre, const float* __restrict__ whh_l,
    unsigned short* __restrict__ whhb) {
  __shared__ unsigned short As[128][88];
  __shared__ unsigned short Bs[128][88];
  const int tid = threadIdx.x;
  {  // fused W_hh fp32->bf16 conversion (independent of the GEMM below)
    const int b = blockIdx.z * 1024 + blockIdx.y * 32 + blockIdx.x;
    const float* src = whh_l + (size_t)b * 4096 + tid * 16;
    unsigned short* dst = whhb + (size_t)b * 4096 + tid * 16;
#pragma unroll
    for (int r = 0; r < 4; ++r) {
      f32x4 v = *(const f32x4*)(src + r * 4);
      u32x2 u2;
      u2[0] = pk2(v[0], v[1]);
      u2[1] = pk2(v[2], v[3]);
      *(u32x2*)(dst + r * 4) = u2;
    }
  }
  const int d = blockIdx.z;
  const int bn0 = blockIdx.x * 128;
  const int bm0 = blockIdx.y * 128;
  const float* Wd = W + (size_t)d * 4096 * 2048;
  const float* bi = bih + d * 4096;
  const float* bh = bhh + d * 4096;
  unsigned short* out = pre + (size_t)d * T_LEN * 4096;

  const int lane = tid & 63;
  const int wid = tid >> 6;
  const int wr = wid >> 1, wc = wid & 1;
  const int fr = lane & 15, fq = lane >> 4;
  const int srow = tid >> 1;
  const int shalf = (tid & 1) * 32;

  f32x4 acc[4][4];
#pragma unroll
  for (int m = 0; m < 4; ++m)
#pragma unroll
    for (int n = 0; n < 4; ++n) acc[m][n] = 0.f;

  for (int k0 = 0; k0 < 2048; k0 += 64) {
    {
      const unsigned short* pA = A + (size_t)(bm0 + srow) * 2048 + k0 + shalf;
#pragma unroll
      for (int q = 0; q < 4; ++q) {
        u32x4 v = *(const u32x4*)(pA + q * 8);
        *(u32x4*)&As[srow][shalf + q * 8] = v;
      }
    }
    {
      const float* pB = Wd + (size_t)(bn0 + srow) * 2048 + k0 + shalf;
#pragma unroll
      for (int q = 0; q < 4; ++q) {
        f32x4 x0 = *(const f32x4*)(pB + q * 8);
        f32x4 x1 = *(const f32x4*)(pB + q * 8 + 4);
        u32x4 u;
        u[0] = pk2(x0[0], x0[1]);
        u[1] = pk2(x0[2], x0[3]);
        u[2] = pk2(x1[0], x1[1]);
        u[3] = pk2(x1[2], x1[3]);
        *(u32x4*)&Bs[srow][shalf + q * 8] = u;
      }
    }
    __syncthreads();
#pragma unroll
    for (int ks = 0; ks < 64; ks += 32) {
      short8 af[4], bfr[4];
#pragma unroll
      for (int m = 0; m < 4; ++m)
        af[m] = *(const short8*)&As[wr * 64 + m * 16 + fr][ks + fq * 8];
#pragma unroll
      for (int n = 0; n < 4; ++n)
        bfr[n] = *(const short8*)&Bs[wc * 64 + n * 16 + fr][ks + fq * 8];
#pragma unroll
      for (int m = 0; m < 4; ++m)
#pragma unroll
        for (int n = 0; n < 4; ++n)
          acc[m][n] = __builtin_amdgcn_mfma_f32_16x16x32_bf16(af[m], bfr[n], acc[m][n], 0, 0, 0);
    }
    __syncthreads();
  }
#pragma unroll
  for (int m = 0; m < 4; ++m) {
#pragma unroll
    for (int n = 0; n < 4; ++n) {
      int col = bn0 + wc * 64 + n * 16 + fr;
      float bias = bi[col] + bh[col];
#pragma unroll
      for (int r = 0; r < 4; ++r) {
        int row = bm0 + wr * 64 + m * 16 + fq * 4 + r;
        out[(size_t)row * 4096 + col] = f2bf(acc[m][n][r] + bias);
      }
    }
  }
}

// ---------------- persistent bidirectional LSTM scan (one layer) ----------------
// 256 WGs x 256 thr. WG 0..127: fwd, 128..255: bwd. Each WAVE owns 2 adjacent units;
// lane l owns h-cols [16l,16l+16). No LDS, no barriers in the loop: each lane polls
// its 4 u64s of the broadcast row straight into the dot2 source registers (2-deep
// ping-pong), full-wave DPP reduce broadcasts sums to all lanes, lane 0 stores.
// hbuf self-cleans: WG0 of each direction re-poisons row s-2 (all its consumers are
// provably done) and rows T-2/T-1 at kernel start.
__global__ __launch_bounds__(256, 1) void lstm_scan(
    const unsigned short* __restrict__ pre,   // [2][T][4096] bf16
    const unsigned short* __restrict__ whhb,  // [2][4096][1024] bf16 (this layer)
    unsigned short* __restrict__ seqout,      // [T][2048] bf16
    unsigned int* __restrict__ hbuf,          // [2][T][512] u32 bf16-pairs
    float* __restrict__ dout, int layer) {
  const int d = blockIdx.x >> 7;
  const int wg = blockIdx.x & 127;
  const int tid = threadIdx.x;
  const int w = tid >> 6;   // wave 0..3
  const int l = tid & 63;   // lane
  const int u0 = wg * 8 + 2 * w;  // this wave's unit pair (u0, u0+1)
  const unsigned int* pre32 = (const unsigned int*)(pre + (size_t)d * T_LEN * 4096);
  const unsigned short* W = whhb + (size_t)d * 4096 * 1024;
  unsigned int* hb = hbuf + (size_t)d * T_LEN * 512;

  // Per-lane W_hh slice: 2 units x 4 gates x cols [16l,16l+16) as packed bf16.
  u32x4 wq[2][4][2];
#pragma unroll
  for (int uu = 0; uu < 2; ++uu)
#pragma unroll
    for (int g = 0; g < 4; ++g)
#pragma unroll
      for (int q = 0; q < 2; ++q)
        wq[uu][g][q] = *(const u32x4*)&W[(size_t)(g * 1024 + u0 + uu) * 1024 + l * 16 + q * 8];
#pragma unroll
  for (int uu = 0; uu < 2; ++uu)
#pragma unroll
    for (int g = 0; g < 4; ++g)
#pragma unroll
      for (int q = 0; q < 2; ++q) asm volatile("" : "+v"(wq[uu][g][q]));  // pin in VGPRs

  if (wg == 0) {  // re-poison rows T-2, T-1 for the next layer (dataflow-ordered)
    unsigned long long* pz = (unsigned long long*)(hb + (size_t)(T_LEN - 2) * 512);
    __hip_atomic_store(pz + tid, SENT64, __ATOMIC_RELAXED, __HIP_MEMORY_SCOPE_AGENT);
    __hip_atomic_store(pz + 256 + tid, SENT64, __ATOMIC_RELAXED, __HIP_MEMORY_SCOPE_AGENT);
  }
  __syncthreads();

  float c0s = 0.f, c1s = 0.f;

  for (int s = 0; s < T_LEN; ++s) {
    const int t = d ? (T_LEN - 1 - s) : s;
    // pre-activations for both units (broadcast loads, hidden under the poll)
    unsigned int pv[4];
#pragma unroll
    for (int g = 0; g < 4; ++g) pv[g] = pre32[(size_t)t * 2048 + g * 512 + wg * 4 + w];

    float a[2][4];
#pragma unroll
    for (int uu = 0; uu < 2; ++uu)
#pragma unroll
      for (int g = 0; g < 4; ++g) a[uu][g] = 0.f;

    if (s > 0) {
      const unsigned long long* src =
          (const unsigned long long*)(hb + (size_t)(s - 1) * 512) + 4 * l;
      unsigned long long A0, A1, A2, A3, B0, B1, B2, B3;
      unsigned long long h0, h1, h2, h3;
#define LD4(X0, X1, X2, X3)                                                   \
  X0 = __hip_atomic_load(src + 0, __ATOMIC_RELAXED, __HIP_MEMORY_SCOPE_AGENT); \
  X1 = __hip_atomic_load(src + 1, __ATOMIC_RELAXED, __HIP_MEMORY_SCOPE_AGENT); \
  X2 = __hip_atomic_load(src + 2, __ATOMIC_RELAXED, __HIP_MEMORY_SCOPE_AGENT); \
  X3 = __hip_atomic_load(src + 3, __ATOMIC_RELAXED, __HIP_MEMORY_SCOPE_AGENT)
      LD4(A0, A1, A2, A3);
      for (;;) {
        LD4(B0, B1, B2, B3);  // keep 8 in flight: sampling period ~ RT/2
        if (okq(A0) && okq(A1) && okq(A2) && okq(A3)) {
          h0 = A0; h1 = A1; h2 = A2; h3 = A3;
          break;
        }
        LD4(A0, A1, A2, A3);
        if (okq(B0) && okq(B1) && okq(B2) && okq(B3)) {
          h0 = B0; h1 = B1; h2 = B2; h3 = B3;
          break;
        }
      }
#undef LD4
      // self-clean: WG0 poisons row s-2 (all consumers provably past it)
      if (wg == 0 && s >= 2) {
        unsigned long long* pz = (unsigned long long*)(hb + (size_t)(s - 2) * 512);
        __hip_atomic_store(pz + tid, SENT64, __ATOMIC_RELAXED, __HIP_MEMORY_SCOPE_AGENT);
      }
      unsigned int hd[8];
      hd[0] = (unsigned int)h0; hd[1] = (unsigned int)(h0 >> 32);
      hd[2] = (unsigned int)h1; hd[3] = (unsigned int)(h1 >> 32);
      hd[4] = (unsigned int)h2; hd[5] = (unsigned int)(h2 >> 32);
      hd[6] = (unsigned int)h3; hd[7] = (unsigned int)(h3 >> 32);
#pragma unroll
      for (int q = 0; q < 2; ++q)
#pragma unroll
        for (int e = 0; e < 4; ++e) {
          const unsigned int hde = hd[q * 4 + e];
#pragma unroll
          for (int uu = 0; uu < 2; ++uu)
#pragma unroll
            for (int g = 0; g < 4; ++g)
              a[uu][g] = dot2bf(wq[uu][g][q][e], hde, a[uu][g]);
        }
    }
    // full-wave reduce, broadcast to all lanes
#pragma unroll
    for (int uu = 0; uu < 2; ++uu)
#pragma unroll
      for (int g = 0; g < 4; ++g) a[uu][g] = wave_sum64(a[uu][g]);

    float h01[2];
#pragma unroll
    for (int uu = 0; uu < 2; ++uu) {
      float pi = bf2f((unsigned short)(uu ? (pv[0] >> 16) : (pv[0] & 0xffffu)));
      float pf = bf2f((unsigned short)(uu ? (pv[1] >> 16) : (pv[1] & 0xffffu)));
      float pg = bf2f((unsigned short)(uu ? (pv[2] >> 16) : (pv[2] & 0xffffu)));
      float po = bf2f((unsigned short)(uu ? (pv[3] >> 16) : (pv[3] & 0xffffu)));
      float iG = sigm(a[uu][0] + pi);
      float fG = sigm(a[uu][1] + pf);
      float gG = tanh_f(a[uu][2] + pg);
      float oG = sigm(a[uu][3] + po);
      float& cs = uu ? c1s : c0s;
      cs = fG * cs + iG * gG;
      h01[uu] = oG * tanh_f(cs);
    }
    if (l == 0) {
      unsigned int hp = pk2(h01[0], h01[1]);
      __hip_atomic_store(hb + (size_t)s * 512 + wg * 4 + w, hp, __ATOMIC_RELAXED,
                         __HIP_MEMORY_SCOPE_AGENT);
      *((unsigned int*)seqout + (size_t)t * 1024 + d * 512 + wg * 4 + w) = hp;
      if (s == T_LEN - 1) {
        dout[4096 + (2 * layer + d) * 1024 + u0] = h01[0];
        dout[4096 + (2 * layer + d) * 1024 + u0 + 1] = h01[1];
        dout[4096 + 6144 + (2 * layer + d) * 1024 + u0] = c0s;
        dout[4096 + 6144 + (2 * layer + d) * 1024 + u0 + 1] = c1s;
      }
    }
  }
}

// ---------------- final FC: sig_out[t] = sigmoid(h_bwd3[t] . fc_w[7] + fc_b[7]) ----------------
__global__ void fc_out(const unsigned short* __restrict__ seq, const float* __restrict__ fcw,
                       const float* __restrict__ fcb, float* __restrict__ out) {
  const int lane = threadIdx.x & 63;
  const int wid = threadIdx.x >> 6;
  const int t = blockIdx.x * 4 + wid;
  if (t >= T_LEN) return;
  const unsigned short* h = seq + (size_t)t * 2048 + 1024;
  const float* w = fcw + 7 * 1024;
  const int j0 = lane * 16;
  float s = 0.f;
#pragma unroll
  for (int q = 0; q < 2; ++q) {
    u32x4 v = *(const u32x4*)(h + j0 + q * 8);
#pragma unroll
    for (int e = 0; e < 4; ++e) {
      float lo = bf2f((unsigned short)(v[e] & 0xffffu));
      float hi = bf2f((unsigned short)(v[e] >> 16));
      s += lo * w[j0 + q * 8 + e * 2] + hi * w[j0 + q * 8 + e * 2 + 1];
    }
  }
#pragma unroll
  for (int m = 32; m >= 1; m >>= 1) s += __shfl_xor(s, m, 64);
  if (lane == 0) out[t] = sigm(s + fcb[7]);
}

extern "C" void kernel_launch(void* const* d_in, const int* in_sizes, int n_in,
                              void* d_out, int out_size, void* d_ws, size_t ws_size,
                              hipStream_t stream) {
  (void)in_sizes; (void)n_in; (void)out_size; (void)ws_size;
  const float* x = (const float*)d_in[0];
  const float* wih = (const float*)d_in[3];
  const float* whh = (const float*)d_in[4];
  const float* bih = (const float*)d_in[5];
  const float* bhh = (const float*)d_in[6];
  const float* fcw = (const float*)d_in[7];
  const float* fcb = (const float*)d_in[8];
  float* out = (float*)d_out;
  char* ws = (char*)d_ws;

  unsigned int* hbuf = (unsigned int*)(ws + 65536);                             // 16 MB
  unsigned short* xbf = (unsigned short*)(ws + 65536 + (size_t)32 * 1048576);   // 16 MB
  unsigned short* seqA = (unsigned short*)(ws + 65536 + (size_t)48 * 1048576);  // 16 MB
  unsigned short* pre = (unsigned short*)(ws + 65536 + (size_t)64 * 1048576);   // 64 MB
  unsigned short* whhb = (unsigned short*)(ws + 65536 + (size_t)128 * 1048576); // 16 MB

  init_conv<<<2048, 256, 0, stream>>>(x, xbf, hbuf);

  const unsigned short* sin_[3] = {xbf, seqA, xbf};
  unsigned short* sout_[3] = {seqA, xbf, seqA};
  for (int l = 0; l < 3; ++l) {
    gemm_pre<<<dim3(32, 32, 2), 256, 0, stream>>>(
        sin_[l], wih + (size_t)l * 2 * 4096 * 2048, bih + l * 8192, bhh + l * 8192, pre,
        whh + (size_t)l * 2 * 4096 * 1024, whhb);

    const unsigned short* preArg = pre;
    const unsigned short* whhArg = whhb;
    unsigned short* soArg = sout_[l];
    unsigned int* hbArg = hbuf;
    float* doutArg = out;
    int layerArg = l;
    void* args[6];
    args[0] = &preArg;
    args[1] = &whhArg;
    args[2] = &soArg;
    args[3] = &hbArg;
    args[4] = &doutArg;
    args[5] = &layerArg;
    (void)hipLaunchCooperativeKernel((void*)lstm_scan, dim3(256), dim3(256), args, 0, stream);
  }
  fc_out<<<1024, 256, 0, stream>>>(seqA, fcw, fcb, out);
}

// Round 6
// 20513.434 us; speedup vs baseline: 5.7071x; 5.7071x over previous
//
#include <hip/hip_runtime.h>

typedef __attribute__((ext_vector_type(4))) float f32x4;
typedef __attribute__((ext_vector_type(8))) short short8;
typedef __attribute__((ext_vector_type(4))) unsigned int u32x4;
typedef __attribute__((ext_vector_type(2))) unsigned int u32x2;

#define T_LEN 4096
#define SENTP 0x7FC07FC0u  // bf16 NaN pair — h is always finite
#define SENT64 0x7FC07FC07FC07FC0ULL

__device__ __forceinline__ float bf2f(unsigned short u) {
  return __uint_as_float(((unsigned int)u) << 16);
}
__device__ __forceinline__ unsigned short f2bf(float f) {
  unsigned int x = __float_as_uint(f);
  unsigned int r = (x + 0x7fffu + ((x >> 16) & 1u)) >> 16;
  return (unsigned short)r;
}
__device__ __forceinline__ unsigned int pk2(float a, float b) {
  return (unsigned int)f2bf(a) | ((unsigned int)f2bf(b) << 16);
}
__device__ __forceinline__ float sigm(float x) { return 1.f / (1.f + __expf(-x)); }
__device__ __forceinline__ float tanh_f(float x) { return 2.f / (1.f + __expf(-2.f * x)) - 1.f; }

#if __has_builtin(__builtin_amdgcn_fdot2_f32_bf16)
typedef __attribute__((ext_vector_type(2))) short bf16x2;
__device__ __forceinline__ float dot2bf(unsigned int w, unsigned int h, float c) {
  bf16x2 a, b;
  __builtin_memcpy(&a, &w, 4);
  __builtin_memcpy(&b, &h, 4);
  return __builtin_amdgcn_fdot2_f32_bf16(a, b, c, false);
}
#else
__device__ __forceinline__ float dot2bf(unsigned int w, unsigned int h, float c) {
  float wl = __uint_as_float(w << 16), wh = __uint_as_float(w & 0xffff0000u);
  float hl = __uint_as_float(h << 16), hh = __uint_as_float(h & 0xffff0000u);
  return c + wl * hl + wh * hh;
}
#endif

__device__ __forceinline__ bool okq(unsigned long long v) {
  return ((unsigned int)v != SENTP) && ((unsigned int)(v >> 32) != SENTP);
}

// DPP row_ror reduction stage (VALU pipe): a += rotate-within-16-row(a).
template <int CTRL>
__device__ __forceinline__ float ror_add(float a) {
  int r = __builtin_amdgcn_update_dpp(0, __float_as_int(a), CTRL, 0xf, 0xf, true);
  return a + __int_as_float(r);
}
// Sum over each 32-lane half of the wave, result broadcast to all 32 lanes of the half.
__device__ __forceinline__ float half_sum32(float a) {
  a = ror_add<0x121>(a);  // row_ror:1
  a = ror_add<0x122>(a);  // row_ror:2
  a = ror_add<0x124>(a);  // row_ror:4
  a = ror_add<0x128>(a);  // row_ror:8  -> 16-row sums on all lanes
  a += __shfl_xor(a, 16, 64);
  return a;
}

// ---------------- init: convert x -> bf16 ----------------
__global__ void init_conv(const float* __restrict__ x, unsigned short* __restrict__ xbf) {
  int gid = blockIdx.x * 256 + threadIdx.x;
  const int stride = gridDim.x * 256;
  const int n4 = (T_LEN * 2048) / 4;
  for (int i = gid; i < n4; i += stride) {
    f32x4 v = *(const f32x4*)(x + (size_t)i * 4);
    u32x2 u;
    u[0] = pk2(v[0], v[1]);
    u[1] = pk2(v[2], v[3]);
    *(u32x2*)(xbf + (size_t)i * 4) = u;
  }
}

// ---------------- poison hbuf to sentinel (before each scan) ----------------
__global__ void poison_hbuf(unsigned int* __restrict__ hbuf) {
  const int gid = blockIdx.x * 256 + threadIdx.x;  // 4096 blocks x 256 thr = 1M
  u32x4 s4;
  s4[0] = s4[1] = s4[2] = s4[3] = SENTP;
  *(u32x4*)(hbuf + (size_t)gid * 4) = s4;
}

// ---------------- pre = seq @ w_ih.T + b_ih + b_hh  (bf16 MFMA GEMM) ----------------
// Prologue: also converts this layer's W_hh (fp32) -> whhb (bf16), 4096 floats/block.
__global__ __launch_bounds__(256) void gemm_pre(
    const unsigned short* __restrict__ A, const float* __restrict__ W,
    const float* __restrict__ bih, const float* __restrict__ bhh,
    unsigned short* __restrict__ pre, const float* __restrict__ whh_l,
    unsigned short* __restrict__ whhb) {
  __shared__ unsigned short As[128][88];
  __shared__ unsigned short Bs[128][88];
  const int tid = threadIdx.x;
  {  // fused W_hh fp32->bf16 conversion (independent of the GEMM below)
    const int b = blockIdx.z * 1024 + blockIdx.y * 32 + blockIdx.x;
    const float* src = whh_l + (size_t)b * 4096 + tid * 16;
    unsigned short* dst = whhb + (size_t)b * 4096 + tid * 16;
#pragma unroll
    for (int r = 0; r < 4; ++r) {
      f32x4 v = *(const f32x4*)(src + r * 4);
      u32x2 u2;
      u2[0] = pk2(v[0], v[1]);
      u2[1] = pk2(v[2], v[3]);
      *(u32x2*)(dst + r * 4) = u2;
    }
  }
  const int d = blockIdx.z;
  const int bn0 = blockIdx.x * 128;
  const int bm0 = blockIdx.y * 128;
  const float* Wd = W + (size_t)d * 4096 * 2048;
  const float* bi = bih + d * 4096;
  const float* bh = bhh + d * 4096;
  unsigned short* out = pre + (size_t)d * T_LEN * 4096;

  const int lane = tid & 63;
  const int wid = tid >> 6;
  const int wr = wid >> 1, wc = wid & 1;
  const int fr = lane & 15, fq = lane >> 4;
  const int srow = tid >> 1;
  const int shalf = (tid & 1) * 32;

  f32x4 acc[4][4];
#pragma unroll
  for (int m = 0; m < 4; ++m)
#pragma unroll
    for (int n = 0; n < 4; ++n) acc[m][n] = 0.f;

  for (int k0 = 0; k0 < 2048; k0 += 64) {
    {
      const unsigned short* pA = A + (size_t)(bm0 + srow) * 2048 + k0 + shalf;
#pragma unroll
      for (int q = 0; q < 4; ++q) {
        u32x4 v = *(const u32x4*)(pA + q * 8);
        *(u32x4*)&As[srow][shalf + q * 8] = v;
      }
    }
    {
      const float* pB = Wd + (size_t)(bn0 + srow) * 2048 + k0 + shalf;
#pragma unroll
      for (int q = 0; q < 4; ++q) {
        f32x4 x0 = *(const f32x4*)(pB + q * 8);
        f32x4 x1 = *(const f32x4*)(pB + q * 8 + 4);
        u32x4 u;
        u[0] = pk2(x0[0], x0[1]);
        u[1] = pk2(x0[2], x0[3]);
        u[2] = pk2(x1[0], x1[1]);
        u[3] = pk2(x1[2], x1[3]);
        *(u32x4*)&Bs[srow][shalf + q * 8] = u;
      }
    }
    __syncthreads();
#pragma unroll
    for (int ks = 0; ks < 64; ks += 32) {
      short8 af[4], bfr[4];
#pragma unroll
      for (int m = 0; m < 4; ++m)
        af[m] = *(const short8*)&As[wr * 64 + m * 16 + fr][ks + fq * 8];
#pragma unroll
      for (int n = 0; n < 4; ++n)
        bfr[n] = *(const short8*)&Bs[wc * 64 + n * 16 + fr][ks + fq * 8];
#pragma unroll
      for (int m = 0; m < 4; ++m)
#pragma unroll
        for (int n = 0; n < 4; ++n)
          acc[m][n] = __builtin_amdgcn_mfma_f32_16x16x32_bf16(af[m], bfr[n], acc[m][n], 0, 0, 0);
    }
    __syncthreads();
  }
#pragma unroll
  for (int m = 0; m < 4; ++m) {
#pragma unroll
    for (int n = 0; n < 4; ++n) {
      int col = bn0 + wc * 64 + n * 16 + fr;
      float bias = bi[col] + bh[col];
#pragma unroll
      for (int r = 0; r < 4; ++r) {
        int row = bm0 + wr * 64 + m * 16 + fq * 4 + r;
        out[(size_t)row * 4096 + col] = f2bf(acc[m][n][r] + bias);
      }
    }
  }
}

// ---------------- persistent bidirectional LSTM scan (one layer) ----------------
// Round-3 topology (proven): 256 WGs x 256 thr; WG 0..127 fwd, 128..255 bwd; each
// thread = (unit ul=tid>>5, col-group cg=tid&31). Per step: each thread polls ONE
// u64 of the broadcast row (dependent-load self-throttled — round 5 showed wider/
// pipelined polling congests the coherence fabric 5x), LDS-stages it (parity dbuf,
// one barrier), 64 dot2 against AGPR-pinned weights, DPP half-wave reduce, all
// lanes compute gates redundantly, wave leader stores the packed h pair.
__global__ __launch_bounds__(256, 1) void lstm_scan(
    const unsigned short* __restrict__ pre,   // [2][T][4096] bf16
    const unsigned short* __restrict__ whhb,  // [2][4096][1024] bf16 (this layer)
    unsigned short* __restrict__ seqout,      // [T][2048] bf16
    unsigned int* __restrict__ hbuf,          // [2][T][512] u32 bf16-pairs
    float* __restrict__ dout, int layer) {
  const int d = blockIdx.x >> 7;
  const int wg = blockIdx.x & 127;
  const int tid = threadIdx.x;
  const int ul = tid >> 5;   // unit_local 0..7
  const int cg = tid & 31;   // column group 0..31 (32 cols each)
  const int u = wg * 8 + ul;
  const unsigned short* preD = pre + (size_t)d * T_LEN * 4096;
  const unsigned short* W = whhb + (size_t)d * 4096 * 1024;
  unsigned int* hb = hbuf + (size_t)d * T_LEN * 512;
  // 18-dword padded rows; b64 reads: lanes cg, cg+16 share a bank pair -> 2-way (free).
  __shared__ unsigned int hs[2][32 * 18];

  // Per-thread W_hh slice: unit u, 4 gates, cols [cg*32, cg*32+32) packed bf16.
  // Pinned in AGPRs: guaranteed on-chip residency (VGPR_Count=52-60 in r3/r5 proves
  // "+v" did not keep them architecturally VGPR-resident).
  u32x4 wq[4][4];
#pragma unroll
  for (int g = 0; g < 4; ++g)
#pragma unroll
    for (int q = 0; q < 4; ++q)
      wq[g][q] = *(const u32x4*)&W[(size_t)(g * 1024 + u) * 1024 + cg * 32 + q * 8];
#pragma unroll
  for (int g = 0; g < 4; ++g)
#pragma unroll
    for (int q = 0; q < 4; ++q) asm volatile("" : "+a"(wq[g][q]));

  const int wa = (tid >> 3) * 18 + (tid & 7) * 2;  // LDS write addr (dwords)
  float cstate = 0.f;

  for (int s = 0; s < T_LEN; ++s) {
    const int t = d ? (T_LEN - 1 - s) : s;
    float pi = 0.f, pf = 0.f, pg = 0.f, po = 0.f;
    if (cg == 0) {  // issue early: hidden under the poll wait
      const unsigned short* pr = preD + (size_t)t * 4096;
      pi = bf2f(pr[u]);
      pf = bf2f(pr[1024 + u]);
      pg = bf2f(pr[2048 + u]);
      po = bf2f(pr[3072 + u]);
    }
    float a[4] = {0.f, 0.f, 0.f, 0.f};
    if (s > 0) {
      const unsigned long long* src =
          (const unsigned long long*)(hb + (size_t)(s - 1) * 512) + tid;
      // dependent-load poll: self-throttled at ~1 request per fabric RT per thread
      unsigned long long v = __hip_atomic_load(src, __ATOMIC_RELAXED, __HIP_MEMORY_SCOPE_AGENT);
      while (!okq(v))
        v = __hip_atomic_load(src, __ATOMIC_RELAXED, __HIP_MEMORY_SCOPE_AGENT);
      u32x2 wv;
      wv[0] = (unsigned int)v;
      wv[1] = (unsigned int)(v >> 32);
      *(u32x2*)&hs[s & 1][wa] = wv;
      __syncthreads();  // hs[s&1] ready (parity dbuf: no second barrier needed)
      const unsigned int* hrow = &hs[s & 1][cg * 18];
#pragma unroll
      for (int q = 0; q < 4; ++q) {
        u32x2 hA = *(const u32x2*)&hrow[4 * q];
        u32x2 hB = *(const u32x2*)&hrow[4 * q + 2];
        unsigned int hd0 = hA[0], hd1 = hA[1], hd2 = hB[0], hd3 = hB[1];
#pragma unroll
        for (int g = 0; g < 4; ++g) {
          a[g] = dot2bf(wq[g][q][0], hd0, a[g]);
          a[g] = dot2bf(wq[g][q][1], hd1, a[g]);
          a[g] = dot2bf(wq[g][q][2], hd2, a[g]);
          a[g] = dot2bf(wq[g][q][3], hd3, a[g]);
        }
      }
    }
    // leaders seed pre BEFORE the reduce: the sum lands on all 32 lanes of the half
    if (cg == 0) {
      a[0] += pi;
      a[1] += pf;
      a[2] += pg;
      a[3] += po;
    }
#pragma unroll
    for (int g = 0; g < 4; ++g) a[g] = half_sum32(a[g]);
    // all lanes compute gates redundantly (identical inputs -> identical results)
    float iG = sigm(a[0]);
    float fG = sigm(a[1]);
    float gG = tanh_f(a[2]);
    float oG = sigm(a[3]);
    cstate = fG * cstate + iG * gG;
    float h = oG * tanh_f(cstate);
    float h_other = __shfl_xor(h, 32, 64);  // other unit of this wave
    if ((tid & 63) == 0) {                  // wave leader: units u, u+1
      unsigned int hp = pk2(h, h_other);
      __hip_atomic_store(hb + (size_t)s * 512 + wg * 4 + (tid >> 6), hp,
                         __ATOMIC_RELAXED, __HIP_MEMORY_SCOPE_AGENT);
      *(unsigned int*)&seqout[(size_t)t * 2048 + d * 1024 + u] = hp;
    }
    if (s == T_LEN - 1 && cg == 0) {
      dout[4096 + (2 * layer + d) * 1024 + u] = h;
      dout[4096 + 6144 + (2 * layer + d) * 1024 + u] = cstate;
    }
  }
}

// ---------------- final FC: sig_out[t] = sigmoid(h_bwd3[t] . fc_w[7] + fc_b[7]) ----------------
__global__ void fc_out(const unsigned short* __restrict__ seq, const float* __restrict__ fcw,
                       const float* __restrict__ fcb, float* __restrict__ out) {
  const int lane = threadIdx.x & 63;
  const int wid = threadIdx.x >> 6;
  const int t = blockIdx.x * 4 + wid;
  if (t >= T_LEN) return;
  const unsigned short* h = seq + (size_t)t * 2048 + 1024;
  const float* w = fcw + 7 * 1024;
  const int j0 = lane * 16;
  float s = 0.f;
#pragma unroll
  for (int q = 0; q < 2; ++q) {
    u32x4 v = *(const u32x4*)(h + j0 + q * 8);
#pragma unroll
    for (int e = 0; e < 4; ++e) {
      float lo = bf2f((unsigned short)(v[e] & 0xffffu));
      float hi = bf2f((unsigned short)(v[e] >> 16));
      s += lo * w[j0 + q * 8 + e * 2] + hi * w[j0 + q * 8 + e * 2 + 1];
    }
  }
#pragma unroll
  for (int m = 32; m >= 1; m >>= 1) s += __shfl_xor(s, m, 64);
  if (lane == 0) out[t] = sigm(s + fcb[7]);
}

extern "C" void kernel_launch(void* const* d_in, const int* in_sizes, int n_in,
                              void* d_out, int out_size, void* d_ws, size_t ws_size,
                              hipStream_t stream) {
  (void)in_sizes; (void)n_in; (void)out_size; (void)ws_size;
  const float* x = (const float*)d_in[0];
  const float* wih = (const float*)d_in[3];
  const float* whh = (const float*)d_in[4];
  const float* bih = (const float*)d_in[5];
  const float* bhh = (const float*)d_in[6];
  const float* fcw = (const float*)d_in[7];
  const float* fcb = (const float*)d_in[8];
  float* out = (float*)d_out;
  char* ws = (char*)d_ws;

  unsigned int* hbuf = (unsigned int*)(ws + 65536);                             // 16 MB
  unsigned short* xbf = (unsigned short*)(ws + 65536 + (size_t)32 * 1048576);   // 16 MB
  unsigned short* seqA = (unsigned short*)(ws + 65536 + (size_t)48 * 1048576);  // 16 MB
  unsigned short* pre = (unsigned short*)(ws + 65536 + (size_t)64 * 1048576);   // 64 MB
  unsigned short* whhb = (unsigned short*)(ws + 65536 + (size_t)128 * 1048576); // 16 MB

  init_conv<<<2048, 256, 0, stream>>>(x, xbf);

  const unsigned short* sin_[3] = {xbf, seqA, xbf};
  unsigned short* sout_[3] = {seqA, xbf, seqA};
  for (int l = 0; l < 3; ++l) {
    gemm_pre<<<dim3(32, 32, 2), 256, 0, stream>>>(
        sin_[l], wih + (size_t)l * 2 * 4096 * 2048, bih + l * 8192, bhh + l * 8192, pre,
        whh + (size_t)l * 2 * 4096 * 1024, whhb);
    poison_hbuf<<<4096, 256, 0, stream>>>(hbuf);

    const unsigned short* preArg = pre;
    const unsigned short* whhArg = whhb;
    unsigned short* soArg = sout_[l];
    unsigned int* hbArg = hbuf;
    float* doutArg = out;
    int layerArg = l;
    void* args[6];
    args[0] = &preArg;
    args[1] = &whhArg;
    args[2] = &soArg;
    args[3] = &hbArg;
    args[4] = &doutArg;
    args[5] = &layerArg;
    (void)hipLaunchCooperativeKernel((void*)lstm_scan, dim3(256), dim3(256), args, 0, stream);
  }
  fc_out<<<1024, 256, 0, stream>>>(seqA, fcw, fcb, out);
}